// Round 8
// baseline (982.833 us; speedup 1.0000x reference)
//
#include <hip/hip_runtime.h>

#define NDEV 8192
#define NAP  4
#define NSAMP 32768
#define EDD 262144
#define EDA 32768
#define EAD 32768
#define CHUNK 4096
#define KC 128
#define ASTR 20

typedef float vf2 __attribute__((ext_vector_type(2)));
typedef short bf16x8 __attribute__((ext_vector_type(8)));
typedef float f32x4v __attribute__((ext_vector_type(4)));
typedef unsigned short u16;

static __device__ __forceinline__ vf2 pk_fma(vf2 a, vf2 b, vf2 c) {
    return __builtin_elementwise_fma(a, b, c);
}
static __device__ __forceinline__ unsigned short f2bf(float f) {
    unsigned u = __float_as_uint(f);
    u += 0x7FFF + ((u >> 16) & 1);
    return (unsigned short)(u >> 16);
}
static __device__ __forceinline__ float bf2f(unsigned short h) {
    return __uint_as_float(((unsigned)h) << 16);
}
// exact 3-way bf16 split (hi+mid+lo reconstructs ~24 mantissa bits)
static __device__ __forceinline__ void split_store4(
    float4 v, u16* ph, u16* pm, u16* pl)
{
    float a[4] = {v.x, v.y, v.z, v.w};
    unsigned short hh[4], mm[4], ll[4];
    #pragma unroll
    for (int i = 0; i < 4; ++i) {
        unsigned short h = f2bf(a[i]);
        float r1 = a[i] - bf2f(h);
        unsigned short m = f2bf(r1);
        float r2 = r1 - bf2f(m);
        hh[i] = h; mm[i] = m; ll[i] = f2bf(r2);
    }
    *(ushort4*)ph = make_ushort4(hh[0], hh[1], hh[2], hh[3]);
    *(ushort4*)pm = make_ushort4(mm[0], mm[1], mm[2], mm[3]);
    *(ushort4*)pl = make_ushort4(ll[0], ll[1], ll[2], ll[3]);
}

// ---------------------------------------------------------------------------
// Repack conv2 weights to vf2 pairs (round-5 proven layout).
// ---------------------------------------------------------------------------
__global__ void repack_kernel(const float* __restrict__ w2, float* __restrict__ wpk)
{
    int i = blockIdx.x * 256 + threadIdx.x;
    if (i < 4608) {
        int h = i & 1, p = i >> 1;
        int k = p % 9, r = p / 9;
        int q = r & 15, ic = r >> 4;
        wpk[i] = w2[(2 * q + h) * 144 + ic * 9 + k];
    }
}

// fcW [2048][64] -> Wt[n][k] bf16 x3 components. Grid 512, coalesced writes.
__global__ __launch_bounds__(256) void repackW_kernel(
    const float* __restrict__ W, u16* __restrict__ Wh,
    u16* __restrict__ Wm, u16* __restrict__ Wl)
{
    int id = blockIdx.x * 256 + threadIdx.x;   // id = n*2048 + k
    int n = id >> 11, k = id & 2047;
    float x = W[k * 64 + n];
    unsigned short h = f2bf(x);
    float r1 = x - bf2f(h);
    unsigned short m = f2bf(r1);
    float r2 = r1 - bf2f(m);
    Wh[id] = h; Wm[id] = m; Wl[id] = f2bf(r2);
}

// ---------------------------------------------------------------------------
// conv1+conv2 (round-5 proven compute), m-major output as bf16x3 components.
// ---------------------------------------------------------------------------
__global__ __launch_bounds__(256) void conv_kernel(
    const float* __restrict__ csi,
    u16* __restrict__ c2h, u16* __restrict__ c2m, u16* __restrict__ c2l,
    const float* __restrict__ w1, const float* __restrict__ b1,
    const float* __restrict__ wpk, const float* __restrict__ b2)
{
    __shared__ float sw1[288];
    __shared__ float sb1[16];
    __shared__ float sb2[32];
    __shared__ float inpad[4][2][10][10];
    __shared__ float c1pad[7712];
    const int tid = threadIdx.x;

    for (int i = tid; i < 288; i += 256) sw1[i] = w1[i];
    if (tid < 16) sb1[tid] = b1[tid];
    if (tid < 32) sb2[tid] = b2[tid];
    float* ip = &inpad[0][0][0][0];
    for (int i = tid; i < 800; i += 256) ip[i] = 0.f;
    for (int i = tid; i < 7712; i += 256) c1pad[i] = 0.f;
    __syncthreads();

    const long s0 = (long)blockIdx.x * 4;
    for (int i = tid; i < 512; i += 256) {
        int si = i >> 7, r = i & 127;
        int f = r >> 4, t = (r >> 1) & 7, c = r & 1;
        inpad[si][c][f + 1][t + 1] = csi[s0 * 128 + i];
    }
    __syncthreads();

    for (int j = 0; j < 16; ++j) {
        int idx = tid + j * 256;
        int t = idx & 7, f = (idx >> 3) & 7, oc = (idx >> 6) & 15, si = idx >> 10;
        float acc = sb1[oc];
        #pragma unroll
        for (int ic = 0; ic < 2; ++ic)
            #pragma unroll
            for (int df = 0; df < 3; ++df)
                #pragma unroll
                for (int dt = 0; dt < 3; ++dt)
                    acc += inpad[si][ic][f + df][t + dt] * sw1[((oc * 2 + ic) * 3 + df) * 3 + dt];
        c1pad[si * 1928 + oc * 120 + (f + 1) * 12 + (t + 1)] = fmaxf(acc, 0.f);
    }
    __syncthreads();

    const int wv = __builtin_amdgcn_readfirstlane(tid >> 6);
    const int lane = tid & 63;
    const int pos = lane & 31;
    const int si = pos >> 3, fr = pos & 7;
    const int th = lane >> 5, tb = th * 4;
    const vf2* __restrict__ wv2 = (const vf2*)wpk;

    vf2 accp[4][4];
    #pragma unroll
    for (int op = 0; op < 4; ++op) {
        int q = wv * 4 + op;
        vf2 b = {sb2[2 * q], sb2[2 * q + 1]};
        #pragma unroll
        for (int t = 0; t < 4; ++t) accp[op][t] = b;
    }

    for (int ic = 0; ic < 16; ++ic) {
        float rr[3][6];
        const int base = si * 1928 + ic * 120 + fr * 12 + tb;
        #pragma unroll
        for (int r = 0; r < 3; ++r) {
            float4 a = *(const float4*)&c1pad[base + r * 12];
            float2 b = *(const float2*)&c1pad[base + r * 12 + 4];
            rr[r][0] = a.x; rr[r][1] = a.y; rr[r][2] = a.z; rr[r][3] = a.w;
            rr[r][4] = b.x; rr[r][5] = b.y;
        }
        const vf2* wp = wv2 + (size_t)(ic * 16 + wv * 4) * 9;
        vf2 w[36];
        #pragma unroll
        for (int u = 0; u < 36; ++u) w[u] = wp[u];
        #pragma unroll
        for (int op = 0; op < 4; ++op) {
            #pragma unroll
            for (int df = 0; df < 3; ++df)
                #pragma unroll
                for (int dt = 0; dt < 3; ++dt) {
                    vf2 wq = w[op * 9 + df * 3 + dt];
                    #pragma unroll
                    for (int t = 0; t < 4; ++t) {
                        vf2 sv = {rr[df][t + dt], rr[df][t + dt]};
                        accp[op][t] = pk_fma(sv, wq, accp[op][t]);
                    }
                }
        }
    }
    #pragma unroll
    for (int op = 0; op < 4; ++op) {
        int q = wv * 4 + op;
        float4 lo, hi;
        lo.x = fmaxf(accp[op][0].x, 0.f); lo.y = fmaxf(accp[op][1].x, 0.f);
        lo.z = fmaxf(accp[op][2].x, 0.f); lo.w = fmaxf(accp[op][3].x, 0.f);
        hi.x = fmaxf(accp[op][0].y, 0.f); hi.y = fmaxf(accp[op][1].y, 0.f);
        hi.z = fmaxf(accp[op][2].y, 0.f); hi.w = fmaxf(accp[op][3].y, 0.f);
        size_t idx = (size_t)(s0 + si) * 2048 + (size_t)(2 * q) * 64 + fr * 8 + tb;
        split_store4(lo, c2h + idx, c2m + idx, c2l + idx);
        split_store4(hi, c2h + idx + 64, c2m + idx + 64, c2l + idx + 64);
    }
}

// ---------------------------------------------------------------------------
// MFMA bf16x3 fc: [CHUNK,2048]@[2048,64] + bias, relu.
// Block: mt (16 samples) x nh (32 cols); 4 waves = 2 n-slabs x 2 K-halves.
// A frags from global c2 (m-major), B frags from global Wt (n-major) —
// both per-lane-contiguous 16B; no LDS in the K-loop.
// ---------------------------------------------------------------------------
__global__ __launch_bounds__(256) void fcm_kernel(
    const u16* __restrict__ c2h, const u16* __restrict__ c2m, const u16* __restrict__ c2l,
    const u16* __restrict__ Wth, const u16* __restrict__ Wtm, const u16* __restrict__ Wtl,
    const float* __restrict__ bias, float* __restrict__ emb)
{
    __shared__ float cred[2][16][16];
    const int tid = threadIdx.x;
    const int wave = __builtin_amdgcn_readfirstlane(tid >> 6);
    const int lane = tid & 63;
    const int l15 = lane & 15;
    const int quad = lane >> 4;
    const int nslab = wave & 1, khalf = wave >> 1;
    const int mt = blockIdx.x >> 1, nh = blockIdx.x & 1;
    const int ncol = nh * 32 + nslab * 16 + l15;

    const size_t abase = (size_t)(mt * 16 + l15) * 2048 + khalf * 1024 + quad * 8;
    const size_t bbase = (size_t)ncol * 2048 + khalf * 1024 + quad * 8;

    f32x4v acc = {0.f, 0.f, 0.f, 0.f};
    #pragma unroll 2
    for (int it = 0; it < 32; ++it) {
        const size_t ao = abase + (size_t)it * 32;
        const size_t bo = bbase + (size_t)it * 32;
        bf16x8 ah = *(const bf16x8*)(c2h + ao);
        bf16x8 am = *(const bf16x8*)(c2m + ao);
        bf16x8 al = *(const bf16x8*)(c2l + ao);
        bf16x8 bh = *(const bf16x8*)(Wth + bo);
        bf16x8 bm = *(const bf16x8*)(Wtm + bo);
        bf16x8 bl = *(const bf16x8*)(Wtl + bo);
        acc = __builtin_amdgcn_mfma_f32_16x16x32_bf16(ah, bh, acc, 0, 0, 0);
        acc = __builtin_amdgcn_mfma_f32_16x16x32_bf16(ah, bm, acc, 0, 0, 0);
        acc = __builtin_amdgcn_mfma_f32_16x16x32_bf16(am, bh, acc, 0, 0, 0);
        acc = __builtin_amdgcn_mfma_f32_16x16x32_bf16(ah, bl, acc, 0, 0, 0);
        acc = __builtin_amdgcn_mfma_f32_16x16x32_bf16(al, bh, acc, 0, 0, 0);
        acc = __builtin_amdgcn_mfma_f32_16x16x32_bf16(am, bm, acc, 0, 0, 0);
    }
    if (khalf == 1)
        *(float4*)&cred[nslab][l15][quad * 4] = make_float4(acc[0], acc[1], acc[2], acc[3]);
    __syncthreads();
    if (khalf == 0) {
        float4 o = *(float4*)&cred[nslab][l15][quad * 4];
        const float b = bias[ncol];
        float r[4];
        r[0] = fmaxf(acc[0] + o.x + b, 0.f);
        r[1] = fmaxf(acc[1] + o.y + b, 0.f);
        r[2] = fmaxf(acc[2] + o.z + b, 0.f);
        r[3] = fmaxf(acc[3] + o.w + b, 0.f);
        float* ep = emb + (size_t)(mt * 16 + quad * 4) * 64 + ncol;
        #pragma unroll
        for (int i = 0; i < 4; ++i) ep[(size_t)i * 64] = r[i];
    }
}

// ---------------------------------------------------------------------------
// fc16 (round-6 form) kept for the K=256 device-csi GEMM only.
// ---------------------------------------------------------------------------
__global__ __launch_bounds__(256) void fc16_kernel(
    const float* __restrict__ A, const float* __restrict__ W,
    const float* __restrict__ bias, float* __restrict__ out, int K)
{
    __shared__ __align__(16) float smem[KC * ASTR + KC * 64];
    float* As = smem;
    float* Ws = smem + KC * ASTR;
    const int tid = threadIdx.x;
    const long m0g = (long)blockIdx.x * 16;
    const int ks = tid >> 6;
    const int lane = tid & 63;
    const int m0 = (lane >> 4) * 4;
    const int o0 = (lane & 15) * 4;

    float4 pa[2], pw[8];
    #pragma unroll
    for (int i = 0; i < 2; ++i) {
        int idx = tid + i * 256; int m = idx & 15, kq = idx >> 4;
        pa[i] = *(const float4*)&A[(m0g + m) * K + kq * 4];
    }
    #pragma unroll
    for (int i = 0; i < 8; ++i) {
        int idx = tid + i * 256; int k = idx >> 4, oq = idx & 15;
        pw[i] = *(const float4*)&W[(long)k * 64 + oq * 4];
    }

    vf2 accp[4][2];
    #pragma unroll
    for (int i = 0; i < 4; ++i) { accp[i][0] = (vf2){0.f, 0.f}; accp[i][1] = (vf2){0.f, 0.f}; }

    const int nk = K / KC;
    for (int kc = 0; kc < nk; ++kc) {
        __syncthreads();
        #pragma unroll
        for (int i = 0; i < 2; ++i) {
            int idx = tid + i * 256; int m = idx & 15, kq = idx >> 4;
            As[(kq * 4 + 0) * ASTR + m] = pa[i].x;
            As[(kq * 4 + 1) * ASTR + m] = pa[i].y;
            As[(kq * 4 + 2) * ASTR + m] = pa[i].z;
            As[(kq * 4 + 3) * ASTR + m] = pa[i].w;
        }
        #pragma unroll
        for (int i = 0; i < 8; ++i) {
            int idx = tid + i * 256; int k = idx >> 4, oq = idx & 15;
            *(float4*)&Ws[k * 64 + oq * 4] = pw[i];
        }
        __syncthreads();
        if (kc + 1 < nk) {
            const int kb2 = (kc + 1) * KC;
            #pragma unroll
            for (int i = 0; i < 2; ++i) {
                int idx = tid + i * 256; int m = idx & 15, kq = idx >> 4;
                pa[i] = *(const float4*)&A[(m0g + m) * K + kb2 + kq * 4];
            }
            #pragma unroll
            for (int i = 0; i < 8; ++i) {
                int idx = tid + i * 256; int k = idx >> 4, oq = idx & 15;
                pw[i] = *(const float4*)&W[(long)(kb2 + k) * 64 + oq * 4];
            }
        }
        const int kb = ks * 32;
        #pragma unroll 8
        for (int kk = 0; kk < 32; ++kk) {
            float4 a4 = *(const float4*)&As[(kb + kk) * ASTR + m0];
            float4 w4 = *(const float4*)&Ws[(kb + kk) * 64 + o0];
            vf2 w01 = {w4.x, w4.y}, w23 = {w4.z, w4.w};
            float av[4] = {a4.x, a4.y, a4.z, a4.w};
            #pragma unroll
            for (int i = 0; i < 4; ++i) {
                vf2 a2 = {av[i], av[i]};
                accp[i][0] = pk_fma(a2, w01, accp[i][0]);
                accp[i][1] = pk_fma(a2, w23, accp[i][1]);
            }
        }
    }
    __syncthreads();
    float* red = smem;
    #pragma unroll
    for (int i = 0; i < 4; ++i) {
        red[(ks * 16 + m0 + i) * 64 + o0 + 0] = accp[i][0].x;
        red[(ks * 16 + m0 + i) * 64 + o0 + 1] = accp[i][0].y;
        red[(ks * 16 + m0 + i) * 64 + o0 + 2] = accp[i][1].x;
        red[(ks * 16 + m0 + i) * 64 + o0 + 3] = accp[i][1].y;
    }
    __syncthreads();
    {
        int m = tid >> 4, oq = tid & 15;
        float4 r0 = *(float4*)&red[(0 * 16 + m) * 64 + oq * 4];
        float4 r1 = *(float4*)&red[(1 * 16 + m) * 64 + oq * 4];
        float4 r2 = *(float4*)&red[(2 * 16 + m) * 64 + oq * 4];
        float4 r3 = *(float4*)&red[(3 * 16 + m) * 64 + oq * 4];
        const float4 b4 = *(const float4*)&bias[oq * 4];
        float4 o4;
        o4.x = fmaxf(r0.x + r1.x + r2.x + r3.x + b4.x, 0.f);
        o4.y = fmaxf(r0.y + r1.y + r2.y + r3.y + b4.y, 0.f);
        o4.z = fmaxf(r0.z + r1.z + r2.z + r3.z + b4.z, 0.f);
        o4.w = fmaxf(r0.w + r1.w + r2.w + r3.w + b4.w, 0.f);
        *(float4*)&out[(m0g + m) * 64 + oq * 4] = o4;
    }
}

// ---------------------------------------------------------------------------
__global__ __launch_bounds__(256) void merge_kernel(
    const float* __restrict__ dpos, const int* __restrict__ pkts,
    const float* __restrict__ csif,
    const float* __restrict__ Wp, const float* __restrict__ bp,
    const float* __restrict__ Wm, const float* __restrict__ bm,
    const int* __restrict__ degout,
    float* __restrict__ hdev, float* __restrict__ xn)
{
    __shared__ float sWm[80][64];
    __shared__ float spos[4][16];
    __shared__ float scf[4][64];
    const int tid = threadIdx.x;
    for (int i = tid; i < 5120; i += 256) sWm[i >> 6][i & 63] = Wm[i];
    const int n0 = blockIdx.x * 4;
    (&scf[0][0])[tid] = csif[(long)n0 * 64 + tid];
    if (tid < 64) {
        int dl = tid >> 4, o = tid & 15;
        int d = n0 + dl;
        float px = dpos[d * 2], py = dpos[d * 2 + 1], pk = (float)pkts[d];
        float v = bp[o] + px * Wp[o] + py * Wp[16 + o] + pk * Wp[32 + o];
        spos[dl][o] = fmaxf(v, 0.f);
    }
    __syncthreads();
    const int o = tid & 63, dl = tid >> 6;
    float h = bm[o];
    #pragma unroll
    for (int j = 0; j < 16; ++j) h += spos[dl][j] * sWm[j][o];
    #pragma unroll 8
    for (int j = 0; j < 64; ++j) h += scf[dl][j] * sWm[16 + j][o];
    h = fmaxf(h, 0.f);
    const long idx = (long)(n0 + dl) * 64 + o;
    hdev[idx] = h;
    xn[idx] = h * rsqrtf(fmaxf((float)degout[n0 + dl], 1.f));
}

__global__ void ap_enc_kernel(const float* __restrict__ appos,
                              const float* __restrict__ W, const float* __restrict__ b,
                              const int* __restrict__ degout,
                              float* __restrict__ hap, float* __restrict__ xnap)
{
    int tid = threadIdx.x;
    int a = tid >> 6, o = tid & 63;
    float v = fmaxf(b[o] + appos[a * 2] * W[o] + appos[a * 2 + 1] * W[64 + o], 0.f);
    hap[tid] = v;
    xnap[tid] = v * rsqrtf(fmaxf((float)degout[a], 1.f));
}

// ---------------------------------------------------------------------------
__global__ __launch_bounds__(256) void degrees_kernel(
    const int* __restrict__ dd_src, const int* __restrict__ dd_dst,
    const int* __restrict__ da_src, const int* __restrict__ da_dst,
    const int* __restrict__ ad_src, const int* __restrict__ ad_dst,
    int* deg_dd_out, int* deg_dd_in, int* deg_da_out, int* deg_ad_in, int* deg_small)
{
    __shared__ int s4[16];
    const int tid = threadIdx.x;
    if (tid < 16) s4[tid] = 0;
    __syncthreads();
    const int gid = blockIdx.x * 256 + tid;
    atomicAdd(&deg_dd_out[dd_src[gid]], 1);
    atomicAdd(&deg_dd_in[dd_dst[gid]], 1);
    if (gid < EDA) {
        atomicAdd(&deg_da_out[da_src[gid]], 1);
        atomicAdd(&s4[da_dst[gid]], 1);
        atomicAdd(&s4[8 + ad_src[gid]], 1);
        atomicAdd(&deg_ad_in[ad_dst[gid]], 1);
    }
    __syncthreads();
    if (tid < 16 && s4[tid] != 0) atomicAdd(&deg_small[tid], s4[tid]);
}

__global__ __launch_bounds__(1024) void scan_kernel(
    const int* __restrict__ degA, int* rsA, int* curA,
    const int* __restrict__ degB, int* rsB, int* curB)
{
    const int* deg = blockIdx.x ? degB : degA;
    int* rs = blockIdx.x ? rsB : rsA;
    int* cur = blockIdx.x ? curB : curA;
    __shared__ int sd[1024];
    const int tid = threadIdx.x;
    const int base = tid * 8;
    int v[8]; int s = 0;
    #pragma unroll
    for (int j = 0; j < 8; ++j) { v[j] = deg[base + j]; s += v[j]; }
    sd[tid] = s;
    __syncthreads();
    for (int off = 1; off < 1024; off <<= 1) {
        int t = (tid >= off) ? sd[tid - off] : 0;
        __syncthreads();
        sd[tid] += t;
        __syncthreads();
    }
    int ex = sd[tid] - s;
    #pragma unroll
    for (int j = 0; j < 8; ++j) { rs[base + j] = ex; cur[base + j] = ex; ex += v[j]; }
}

__global__ __launch_bounds__(256) void reorder_kernel(
    const int* __restrict__ src, const int* __restrict__ dst,
    int* __restrict__ cursor, int* __restrict__ ssrc, int nE)
{
    int e = blockIdx.x * 256 + threadIdx.x;
    if (e < nE) {
        int pos = atomicAdd(&cursor[dst[e]], 1);
        ssrc[pos] = src[e];
    }
}

// ---------------------------------------------------------------------------
__global__ __launch_bounds__(256) void gather_kernel(
    const int* __restrict__ row_start, const int* __restrict__ deg_in,
    const int* __restrict__ ssrc, const float* __restrict__ xn,
    float* __restrict__ agg)
{
    const int tid = threadIdx.x;
    const int w = __builtin_amdgcn_readfirstlane(tid >> 6);
    const int f = tid & 63;
    const int d = blockIdx.x * 4 + w;
    const int start = row_start[d], len = deg_in[d];
    float acc = 0.f;
    int j = 0;
    for (; j + 4 <= len; j += 4) {
        int s0 = ssrc[start + j], s1 = ssrc[start + j + 1];
        int s2 = ssrc[start + j + 2], s3 = ssrc[start + j + 3];
        float v0 = xn[(long)s0 * 64 + f], v1 = xn[(long)s1 * 64 + f];
        float v2 = xn[(long)s2 * 64 + f], v3 = xn[(long)s3 * 64 + f];
        acc += (v0 + v1) + (v2 + v3);
    }
    for (; j < len; ++j) acc += xn[(long)ssrc[start + j] * 64 + f];
    agg[(long)d * 64 + f] = acc * rsqrtf(fmaxf((float)len, 1.f));
}

__global__ __launch_bounds__(256) void da_reduce_kernel(
    const int* __restrict__ src, const int* __restrict__ dst,
    const float* __restrict__ x, const int* __restrict__ deg_out,
    float* __restrict__ agg)
{
    __shared__ float sacc[4][64];
    const int tid = threadIdx.x;
    (&sacc[0][0])[tid] = 0.f;
    __syncthreads();
    const int f = tid & 63;
    const int base = blockIdx.x * 128;
    for (int e = base + (tid >> 6); e < base + 128; e += 4) {
        int s = src[e], d = dst[e];
        float sc = rsqrtf(fmaxf((float)deg_out[s], 1.f));
        atomicAdd(&sacc[d][f], x[(long)s * 64 + f] * sc);
    }
    __syncthreads();
    float v = (&sacc[0][0])[tid];
    if (v != 0.f) atomicAdd(&agg[tid], v);
}

// ---------------------------------------------------------------------------
__global__ __launch_bounds__(256) void combine_hd_kernel(
    const float* __restrict__ agg1, const float* __restrict__ W1, const float* __restrict__ b1,
    const float* __restrict__ agg2, const float* __restrict__ W2, const float* __restrict__ b2,
    const int* __restrict__ degout, float* __restrict__ out, float* __restrict__ xnout)
{
    __shared__ float sW1[64][64];
    __shared__ float sW2[64][64];
    __shared__ float sa1[4][64];
    __shared__ float sa2[4][64];
    const int tid = threadIdx.x;
    for (int i = tid; i < 4096; i += 256) { sW1[i >> 6][i & 63] = W1[i]; sW2[i >> 6][i & 63] = W2[i]; }
    const int n0 = blockIdx.x * 4;
    (&sa1[0][0])[tid] = agg1[(long)n0 * 64 + tid];
    (&sa2[0][0])[tid] = agg2[(long)n0 * 64 + tid];
    __syncthreads();
    const int o = tid & 63, dl = tid >> 6;
    float acc1 = 0.f, acc2 = 0.f;
    #pragma unroll 8
    for (int k = 0; k < 64; ++k) {
        acc1 += sa1[dl][k] * sW1[k][o];
        acc2 += sa2[dl][k] * sW2[k][o];
    }
    float h = fmaxf(acc1 + acc2 + b1[o] + b2[o], 0.f);
    const long idx = (long)(n0 + dl) * 64 + o;
    out[idx] = h;
    if (xnout) xnout[idx] = h * rsqrtf(fmaxf((float)degout[n0 + dl], 1.f));
}

__global__ void combine_ha_kernel(const float* __restrict__ agg, const int* __restrict__ degin,
                                  const float* __restrict__ W, const float* __restrict__ b,
                                  const int* __restrict__ degout,
                                  float* __restrict__ out, float* __restrict__ xnout)
{
    const int tid = threadIdx.x;
    const int o = tid & 63, a = tid >> 6;
    float acc = 0.f;
    for (int k = 0; k < 64; ++k) acc += agg[a * 64 + k] * W[k * 64 + o];
    float r = rsqrtf(fmaxf((float)degin[a], 1.f));
    float h = fmaxf(acc * r + b[o], 0.f);
    out[tid] = h;
    xnout[tid] = h * rsqrtf(fmaxf((float)degout[a], 1.f));
}

// ---------------------------------------------------------------------------
__global__ __launch_bounds__(256) void head_kernel(
    const float* __restrict__ hd2,
    const float* __restrict__ W1, const float* __restrict__ b1,
    const float* __restrict__ W2, const float* __restrict__ b2,
    float* __restrict__ logits_out)
{
    __shared__ float sW1[64][64];
    __shared__ float sW2[64][32];
    __shared__ float sh[4][64];
    __shared__ float st[4][64];
    const int tid = threadIdx.x;
    for (int i = tid; i < 4096; i += 256) sW1[i >> 6][i & 63] = W1[i];
    for (int i = tid; i < 2048; i += 256) sW2[i >> 5][i & 31] = W2[i];
    const int n0 = blockIdx.x * 4;
    (&sh[0][0])[tid] = hd2[(long)n0 * 64 + tid];
    __syncthreads();
    const int o = tid & 63, dl = tid >> 6;
    float acc = b1[o];
    #pragma unroll 8
    for (int k = 0; k < 64; ++k) acc += sh[dl][k] * sW1[k][o];
    st[dl][o] = fmaxf(acc, 0.f);
    __syncthreads();
    if (tid < 128) {
        int j = tid & 31, d2 = tid >> 5;
        float a2 = b2[j];
        #pragma unroll 8
        for (int k = 0; k < 64; ++k) a2 += st[d2][k] * sW2[k][j];
        logits_out[(long)(n0 + d2) * 32 + j] = a2;
    }
}

// ---------------------------------------------------------------------------
__global__ __launch_bounds__(1024) void softmax_stats_kernel(
    const float* __restrict__ logits,
    float* __restrict__ smax, int* __restrict__ sargm, float* __restrict__ ssum)
{
    __shared__ float smx[1024];
    __shared__ int sid[1024];
    __shared__ float ssm[1024];
    const int j = blockIdx.x;
    const int tid = threadIdx.x;
    float best = -__builtin_inff(); int bid = 0x7fffffff;
    for (int n = tid; n < NDEV; n += 1024) {
        float v = logits[n * 32 + j];
        if (v > best) { best = v; bid = n; }
    }
    smx[tid] = best; sid[tid] = bid;
    __syncthreads();
    for (int s = 512; s > 0; s >>= 1) {
        if (tid < s) {
            float v2 = smx[tid + s]; int i2 = sid[tid + s];
            if (v2 > smx[tid] || (v2 == smx[tid] && i2 < sid[tid])) { smx[tid] = v2; sid[tid] = i2; }
        }
        __syncthreads();
    }
    const float mx = smx[0];
    float part = 0.f;
    for (int n = tid; n < NDEV; n += 1024) part += expf(logits[n * 32 + j] - mx);
    ssm[tid] = part;
    __syncthreads();
    for (int s = 512; s > 0; s >>= 1) {
        if (tid < s) ssm[tid] += ssm[tid + s];
        __syncthreads();
    }
    if (tid == 0) { smax[j] = mx; sargm[j] = sid[0]; ssum[j] = ssm[0]; }
}

__global__ __launch_bounds__(256) void final_kernel(
    const float* __restrict__ logits, const float* __restrict__ smax,
    const int* __restrict__ sargm, const float* __restrict__ ssum,
    float* __restrict__ hard, float* __restrict__ soft)
{
    const int gid = blockIdx.x * 256 + threadIdx.x;
    const int n = gid >> 3, t = gid & 7;
    float s = 0.f; int h = 0;
    #pragma unroll
    for (int a = 0; a < 4; ++a) {
        int j = t * 4 + a;
        s += expf(logits[n * 32 + j] - smax[j]) / ssum[j];
        h |= (sargm[j] == n) ? 1 : 0;
    }
    hard[gid] = (float)h;
    soft[gid] = s;
}

// ---------------------------------------------------------------------------
extern "C" void kernel_launch(void* const* d_in, const int* in_sizes, int n_in,
                              void* d_out, int out_size, void* d_ws, size_t ws_size,
                              hipStream_t stream)
{
    const float* device_pos = (const float*)d_in[0];
    const float* ap_pos     = (const float*)d_in[1];
    const float* csi        = (const float*)d_in[2];
    const int*   node_pk    = (const int*)d_in[3];
    const int* dd_src = (const int*)d_in[4];
    const int* dd_dst = (const int*)d_in[5];
    const int* da_src = (const int*)d_in[6];
    const int* da_dst = (const int*)d_in[7];
    const int* ad_src = (const int*)d_in[8];
    const int* ad_dst = (const int*)d_in[9];
    const float* w1  = (const float*)d_in[10]; const float* b1  = (const float*)d_in[11];
    const float* w2  = (const float*)d_in[12]; const float* b2  = (const float*)d_in[13];
    const float* fcW = (const float*)d_in[14]; const float* fcb = (const float*)d_in[15];
    const float* Wp  = (const float*)d_in[16]; const float* bp  = (const float*)d_in[17];
    const float* Wc  = (const float*)d_in[18]; const float* bc  = (const float*)d_in[19];
    const float* Wm  = (const float*)d_in[20]; const float* bm  = (const float*)d_in[21];
    const float* Wap = (const float*)d_in[22]; const float* bap = (const float*)d_in[23];
    const float* g1ddW = (const float*)d_in[24]; const float* g1ddb = (const float*)d_in[25];
    const float* g1daW = (const float*)d_in[26]; const float* g1dab = (const float*)d_in[27];
    const float* g1adW = (const float*)d_in[28]; const float* g1adb = (const float*)d_in[29];
    const float* g2ddW = (const float*)d_in[30]; const float* g2ddb = (const float*)d_in[31];
    const float* g2adW = (const float*)d_in[34]; const float* g2adb = (const float*)d_in[35];
    const float* a1W = (const float*)d_in[36]; const float* a1b = (const float*)d_in[37];
    const float* a2W = (const float*)d_in[38]; const float* a2b = (const float*)d_in[39];

    float* ws = (float*)d_ws;
    // float-unit offsets; c2/Wt regions hold ushorts (2 per float slot)
    size_t o_c2h  = 0;                                // CHUNK*2048 u16 = CHUNK*1024 fl
    size_t o_c2m  = o_c2h + (size_t)CHUNK * 1024;
    size_t o_c2l  = o_c2m + (size_t)CHUNK * 1024;
    size_t o_wth  = o_c2l + (size_t)CHUNK * 1024;     // 131072 u16 = 65536 fl
    size_t o_wtm  = o_wth + 65536;
    size_t o_wtl  = o_wtm + 65536;
    size_t o_emb  = o_wtl + 65536;                    // NSAMP*64
    size_t o_csif = o_emb + (size_t)NSAMP * 64;
    size_t o_hdev = o_csif + (size_t)NDEV * 64;
    size_t o_hap  = o_hdev + (size_t)NDEV * 64;       // 256
    size_t o_hd1  = o_hap + 256;
    size_t o_ha1  = o_hd1 + (size_t)NDEV * 64;        // 256
    size_t o_hd2  = o_ha1 + 256;
    size_t o_aggdd = o_hd2 + (size_t)NDEV * 64;
    size_t o_aggad = o_aggdd + (size_t)NDEV * 64;
    size_t o_xn    = o_aggad + (size_t)NDEV * 64;
    size_t o_xnap  = o_xn + (size_t)NDEV * 64;        // 256
    size_t o_wpk   = o_xnap + 256;                    // 4608
    // zero region
    size_t o_zero  = o_wpk + 4608;
    size_t o_degddo = o_zero;
    size_t o_degddi = o_degddo + NDEV;
    size_t o_degdao = o_degddi + NDEV;
    size_t o_degadi = o_degdao + NDEV;
    size_t o_degsm  = o_degadi + NDEV;        // int[16]
    size_t o_aggda  = o_degsm + 16;           // float[256]
    size_t o_zend   = o_aggda + 256;
    // non-zeroed
    size_t o_rsdd  = o_zend;
    size_t o_curdd = o_rsdd + NDEV;
    size_t o_rsad  = o_curdd + NDEV;
    size_t o_curad = o_rsad + NDEV;
    size_t o_ssdd  = o_curad + NDEV;          // int[262144]
    size_t o_ssad  = o_ssdd + EDD;            // int[32768]
    size_t o_smax  = o_ssad + EAD;
    size_t o_ssum  = o_smax + 32;
    size_t o_sargm = o_ssum + 32;

    u16* c2h = (u16*)(ws + o_c2h);
    u16* c2m = (u16*)(ws + o_c2m);
    u16* c2l = (u16*)(ws + o_c2l);
    u16* wth = (u16*)(ws + o_wth);
    u16* wtm = (u16*)(ws + o_wtm);
    u16* wtl = (u16*)(ws + o_wtl);

    float* out = (float*)d_out;
    float* out_hard   = out;                 // [8192][8]
    float* out_logits = out + 65536;         // [8192][32]
    float* out_soft   = out + 65536 + 262144;

    hipMemsetAsync((void*)(ws + o_zero), 0, (o_zend - o_zero) * sizeof(float), stream);
    repack_kernel<<<18, 256, 0, stream>>>(w2, ws + o_wpk);
    repackW_kernel<<<512, 256, 0, stream>>>(fcW, wth, wtm, wtl);

    // graph prep
    degrees_kernel<<<EDD / 256, 256, 0, stream>>>(dd_src, dd_dst, da_src, da_dst, ad_src, ad_dst,
                                                  (int*)(ws + o_degddo), (int*)(ws + o_degddi),
                                                  (int*)(ws + o_degdao), (int*)(ws + o_degadi),
                                                  (int*)(ws + o_degsm));
    scan_kernel<<<2, 1024, 0, stream>>>((int*)(ws + o_degddi), (int*)(ws + o_rsdd), (int*)(ws + o_curdd),
                                        (int*)(ws + o_degadi), (int*)(ws + o_rsad), (int*)(ws + o_curad));
    reorder_kernel<<<EDD / 256, 256, 0, stream>>>(dd_src, dd_dst, (int*)(ws + o_curdd),
                                                  (int*)(ws + o_ssdd), EDD);
    reorder_kernel<<<EAD / 256, 256, 0, stream>>>(ad_src, ad_dst, (int*)(ws + o_curad),
                                                  (int*)(ws + o_ssad), EAD);

    // CSI encoder: conv (f32 -> bf16x3) + MFMA fc
    for (int c = 0; c < NSAMP / CHUNK; ++c) {
        const float* csi_c = csi + (size_t)c * CHUNK * 128;
        float* emb_c = ws + o_emb + (size_t)c * CHUNK * 64;
        conv_kernel<<<CHUNK / 4, 256, 0, stream>>>(csi_c, c2h, c2m, c2l, w1, b1, ws + o_wpk, b2);
        fcm_kernel<<<(CHUNK / 16) * 2, 256, 0, stream>>>(c2h, c2m, c2l, wth, wtm, wtl, fcb, emb_c);
    }

    // device encoder
    fc16_kernel<<<NDEV / 16, 256, 0, stream>>>(ws + o_emb, Wc, bc, ws + o_csif, 256);
    merge_kernel<<<NDEV / 4, 256, 0, stream>>>(device_pos, node_pk, ws + o_csif,
                                               Wp, bp, Wm, bm, (int*)(ws + o_degddo),
                                               ws + o_hdev, ws + o_xn);
    ap_enc_kernel<<<1, 256, 0, stream>>>(ap_pos, Wap, bap, (int*)(ws + o_degsm) + 8,
                                         ws + o_hap, ws + o_xnap);

    // layer 1
    gather_kernel<<<NDEV / 4, 256, 0, stream>>>((int*)(ws + o_rsdd), (int*)(ws + o_degddi),
                                                (int*)(ws + o_ssdd), ws + o_xn, ws + o_aggdd);
    gather_kernel<<<NDEV / 4, 256, 0, stream>>>((int*)(ws + o_rsad), (int*)(ws + o_degadi),
                                                (int*)(ws + o_ssad), ws + o_xnap, ws + o_aggad);
    da_reduce_kernel<<<EDA / 128, 256, 0, stream>>>(da_src, da_dst, ws + o_hdev,
                                                    (int*)(ws + o_degdao), ws + o_aggda);
    combine_hd_kernel<<<NDEV / 4, 256, 0, stream>>>(ws + o_aggdd, g1ddW, g1ddb,
                                                    ws + o_aggad, g1adW, g1adb,
                                                    (int*)(ws + o_degddo), ws + o_hd1, ws + o_xn);
    combine_ha_kernel<<<1, 256, 0, stream>>>(ws + o_aggda, (int*)(ws + o_degsm),
                                             g1daW, g1dab, (int*)(ws + o_degsm) + 8,
                                             ws + o_ha1, ws + o_xnap);

    // layer 2
    gather_kernel<<<NDEV / 4, 256, 0, stream>>>((int*)(ws + o_rsdd), (int*)(ws + o_degddi),
                                                (int*)(ws + o_ssdd), ws + o_xn, ws + o_aggdd);
    gather_kernel<<<NDEV / 4, 256, 0, stream>>>((int*)(ws + o_rsad), (int*)(ws + o_degadi),
                                                (int*)(ws + o_ssad), ws + o_xnap, ws + o_aggad);
    combine_hd_kernel<<<NDEV / 4, 256, 0, stream>>>(ws + o_aggdd, g2ddW, g2ddb,
                                                    ws + o_aggad, g2adW, g2adb,
                                                    (int*)(ws + o_degddo), ws + o_hd2, nullptr);

    head_kernel<<<NDEV / 4, 256, 0, stream>>>(ws + o_hd2, a1W, a1b, a2W, a2b, out_logits);

    softmax_stats_kernel<<<32, 1024, 0, stream>>>(out_logits, ws + o_smax,
                                                  (int*)(ws + o_sargm), ws + o_ssum);
    final_kernel<<<65536 / 256, 256, 0, stream>>>(out_logits, ws + o_smax,
                                                  (int*)(ws + o_sargm), ws + o_ssum,
                                                  out_hard, out_soft);
    (void)in_sizes; (void)n_in; (void)out_size; (void)ws_size;
}

// Round 9
// 705.878 us; speedup vs baseline: 1.3924x; 1.3924x over previous
//
#include <hip/hip_runtime.h>

#define NDEV 8192
#define NAP  4
#define NSAMP 32768
#define EDD 262144
#define EDA 32768
#define EAD 32768
#define CHUNK 8192
#define KC 128
#define ASTR2 132   // As row stride (m-major): 16B-aligned, 4-way stores, free reads

typedef float vf2 __attribute__((ext_vector_type(2)));
static __device__ __forceinline__ vf2 pk_fma(vf2 a, vf2 b, vf2 c) {
    return __builtin_elementwise_fma(a, b, c);
}

// ---------------------------------------------------------------------------
// Repack conv2 weights to vf2 pairs (round-5 proven layout).
// ---------------------------------------------------------------------------
__global__ void repack_kernel(const float* __restrict__ w2, float* __restrict__ wpk)
{
    int i = blockIdx.x * 256 + threadIdx.x;
    if (i < 4608) {
        int h = i & 1, p = i >> 1;
        int k = p % 9, r = p / 9;
        int q = r & 15, ic = r >> 4;
        wpk[i] = w2[(2 * q + h) * 144 + ic * 9 + k];
    }
}

// ---------------------------------------------------------------------------
// conv1+conv2 (round-5 proven kernel, m-major f32 output).
// ---------------------------------------------------------------------------
__global__ __launch_bounds__(256) void conv_kernel(
    const float* __restrict__ csi,
    float* __restrict__ c2,
    const float* __restrict__ w1, const float* __restrict__ b1,
    const float* __restrict__ wpk, const float* __restrict__ b2)
{
    __shared__ float sw1[288];
    __shared__ float sb1[16];
    __shared__ float sb2[32];
    __shared__ float inpad[4][2][10][10];
    __shared__ float c1pad[7712];
    const int tid = threadIdx.x;

    for (int i = tid; i < 288; i += 256) sw1[i] = w1[i];
    if (tid < 16) sb1[tid] = b1[tid];
    if (tid < 32) sb2[tid] = b2[tid];
    float* ip = &inpad[0][0][0][0];
    for (int i = tid; i < 800; i += 256) ip[i] = 0.f;
    for (int i = tid; i < 7712; i += 256) c1pad[i] = 0.f;
    __syncthreads();

    const long s0 = (long)blockIdx.x * 4;
    for (int i = tid; i < 512; i += 256) {
        int si = i >> 7, r = i & 127;
        int f = r >> 4, t = (r >> 1) & 7, c = r & 1;
        inpad[si][c][f + 1][t + 1] = csi[s0 * 128 + i];
    }
    __syncthreads();

    for (int j = 0; j < 16; ++j) {
        int idx = tid + j * 256;
        int t = idx & 7, f = (idx >> 3) & 7, oc = (idx >> 6) & 15, si = idx >> 10;
        float acc = sb1[oc];
        #pragma unroll
        for (int ic = 0; ic < 2; ++ic)
            #pragma unroll
            for (int df = 0; df < 3; ++df)
                #pragma unroll
                for (int dt = 0; dt < 3; ++dt)
                    acc += inpad[si][ic][f + df][t + dt] * sw1[((oc * 2 + ic) * 3 + df) * 3 + dt];
        c1pad[si * 1928 + oc * 120 + (f + 1) * 12 + (t + 1)] = fmaxf(acc, 0.f);
    }
    __syncthreads();

    const int wv = __builtin_amdgcn_readfirstlane(tid >> 6);
    const int lane = tid & 63;
    const int pos = lane & 31;
    const int si = pos >> 3, fr = pos & 7;
    const int th = lane >> 5, tb = th * 4;
    const vf2* __restrict__ wv2 = (const vf2*)wpk;

    vf2 accp[4][4];
    #pragma unroll
    for (int op = 0; op < 4; ++op) {
        int q = wv * 4 + op;
        vf2 b = {sb2[2 * q], sb2[2 * q + 1]};
        #pragma unroll
        for (int t = 0; t < 4; ++t) accp[op][t] = b;
    }

    for (int ic = 0; ic < 16; ++ic) {
        float rr[3][6];
        const int base = si * 1928 + ic * 120 + fr * 12 + tb;
        #pragma unroll
        for (int r = 0; r < 3; ++r) {
            float4 a = *(const float4*)&c1pad[base + r * 12];
            float2 b = *(const float2*)&c1pad[base + r * 12 + 4];
            rr[r][0] = a.x; rr[r][1] = a.y; rr[r][2] = a.z; rr[r][3] = a.w;
            rr[r][4] = b.x; rr[r][5] = b.y;
        }
        const vf2* wp = wv2 + (size_t)(ic * 16 + wv * 4) * 9;
        vf2 w[36];
        #pragma unroll
        for (int u = 0; u < 36; ++u) w[u] = wp[u];
        #pragma unroll
        for (int op = 0; op < 4; ++op) {
            #pragma unroll
            for (int df = 0; df < 3; ++df)
                #pragma unroll
                for (int dt = 0; dt < 3; ++dt) {
                    vf2 wq = w[op * 9 + df * 3 + dt];
                    #pragma unroll
                    for (int t = 0; t < 4; ++t) {
                        vf2 sv = {rr[df][t + dt], rr[df][t + dt]};
                        accp[op][t] = pk_fma(sv, wq, accp[op][t]);
                    }
                }
        }
    }
    #pragma unroll
    for (int op = 0; op < 4; ++op) {
        int q = wv * 4 + op;
        float4 lo, hi;
        lo.x = fmaxf(accp[op][0].x, 0.f); lo.y = fmaxf(accp[op][1].x, 0.f);
        lo.z = fmaxf(accp[op][2].x, 0.f); lo.w = fmaxf(accp[op][3].x, 0.f);
        hi.x = fmaxf(accp[op][0].y, 0.f); hi.y = fmaxf(accp[op][1].y, 0.f);
        hi.z = fmaxf(accp[op][2].y, 0.f); hi.w = fmaxf(accp[op][3].y, 0.f);
        *(float4*)&c2[(s0 + si) * 2048 + (long)(2 * q) * 64 + fr * 8 + tb] = lo;
        *(float4*)&c2[(s0 + si) * 2048 + (long)(2 * q + 1) * 64 + fr * 8 + tb] = hi;
    }
}

// ---------------------------------------------------------------------------
// GEMM [M,K] @ [K,64] + bias, relu. M-tile 16, 4-way K split.
// Round-5 global mappings; As now M-MAJOR stride-132: float4 stores 4-way
// (was 32-way b32), reads 16-lane-broadcast 2-way (free), 16B-aligned.
// ---------------------------------------------------------------------------
__global__ __launch_bounds__(256) void fc16_kernel(
    const float* __restrict__ A, const float* __restrict__ W,
    const float* __restrict__ bias, float* __restrict__ out, int K)
{
    __shared__ __align__(16) float smem[16 * ASTR2 + KC * 64];  // 2112 + 8192
    float* As = smem;               // [16][ASTR2] m-major
    float* Ws = smem + 16 * ASTR2;  // [KC][64]
    const int tid = threadIdx.x;
    const long m0g = (long)blockIdx.x * 16;
    const int ks = tid >> 6;
    const int lane = tid & 63;
    const int m0 = (lane >> 4) * 4;
    const int o0 = (lane & 15) * 4;

    vf2 accp[4][2];
    #pragma unroll
    for (int i = 0; i < 4; ++i) { accp[i][0] = (vf2){0.f, 0.f}; accp[i][1] = (vf2){0.f, 0.f}; }

    for (int kc = 0; kc < K; kc += KC) {
        __syncthreads();
        #pragma unroll
        for (int i = 0; i < 2; ++i) {
            int idx = tid + i * 256;
            int m = idx >> 5, kq = idx & 31;          // kq-fast: coalesced global read
            float4 v = *(const float4*)&A[(m0g + m) * K + kc + kq * 4];
            *(float4*)&As[m * ASTR2 + kq * 4] = v;    // m-major store: 4-way max
        }
        #pragma unroll
        for (int i = 0; i < 8; ++i) {
            int idx = tid + i * 256;
            int k = idx >> 4, oq = idx & 15;
            *(float4*)&Ws[k * 64 + oq * 4] = *(const float4*)&W[(long)(kc + k) * 64 + oq * 4];
        }
        __syncthreads();
        const int kb = ks * 32;
        #pragma unroll 4
        for (int kk4 = 0; kk4 < 8; ++kk4) {
            const int k0 = kb + kk4 * 4;
            float4 a[4], w[4];
            #pragma unroll
            for (int i = 0; i < 4; ++i) a[i] = *(const float4*)&As[(m0 + i) * ASTR2 + k0];
            #pragma unroll
            for (int j = 0; j < 4; ++j) w[j] = *(const float4*)&Ws[(k0 + j) * 64 + o0];
            #pragma unroll
            for (int j = 0; j < 4; ++j) {
                vf2 w01 = {w[j].x, w[j].y}, w23 = {w[j].z, w[j].w};
                float av[4] = {j == 0 ? a[0].x : (j == 1 ? a[0].y : (j == 2 ? a[0].z : a[0].w)),
                               j == 0 ? a[1].x : (j == 1 ? a[1].y : (j == 2 ? a[1].z : a[1].w)),
                               j == 0 ? a[2].x : (j == 1 ? a[2].y : (j == 2 ? a[2].z : a[2].w)),
                               j == 0 ? a[3].x : (j == 1 ? a[3].y : (j == 2 ? a[3].z : a[3].w))};
                #pragma unroll
                for (int i = 0; i < 4; ++i) {
                    vf2 a2 = {av[i], av[i]};
                    accp[i][0] = pk_fma(a2, w01, accp[i][0]);
                    accp[i][1] = pk_fma(a2, w23, accp[i][1]);
                }
            }
        }
    }
    __syncthreads();
    float* red = smem;  // [4][16][64]
    #pragma unroll
    for (int i = 0; i < 4; ++i) {
        red[(ks * 16 + m0 + i) * 64 + o0 + 0] = accp[i][0].x;
        red[(ks * 16 + m0 + i) * 64 + o0 + 1] = accp[i][0].y;
        red[(ks * 16 + m0 + i) * 64 + o0 + 2] = accp[i][1].x;
        red[(ks * 16 + m0 + i) * 64 + o0 + 3] = accp[i][1].y;
    }
    __syncthreads();
    {
        int m = tid >> 4, oq = tid & 15;
        float4 r0 = *(float4*)&red[(0 * 16 + m) * 64 + oq * 4];
        float4 r1 = *(float4*)&red[(1 * 16 + m) * 64 + oq * 4];
        float4 r2 = *(float4*)&red[(2 * 16 + m) * 64 + oq * 4];
        float4 r3 = *(float4*)&red[(3 * 16 + m) * 64 + oq * 4];
        const float4 b4 = *(const float4*)&bias[oq * 4];
        float4 o4;
        o4.x = fmaxf(r0.x + r1.x + r2.x + r3.x + b4.x, 0.f);
        o4.y = fmaxf(r0.y + r1.y + r2.y + r3.y + b4.y, 0.f);
        o4.z = fmaxf(r0.z + r1.z + r2.z + r3.z + b4.z, 0.f);
        o4.w = fmaxf(r0.w + r1.w + r2.w + r3.w + b4.w, 0.f);
        *(float4*)&out[(m0g + m) * 64 + oq * 4] = o4;
    }
}

// ---------------------------------------------------------------------------
// Device merge + fused xnorm.
// ---------------------------------------------------------------------------
__global__ __launch_bounds__(256) void merge_kernel(
    const float* __restrict__ dpos, const int* __restrict__ pkts,
    const float* __restrict__ csif,
    const float* __restrict__ Wp, const float* __restrict__ bp,
    const float* __restrict__ Wm, const float* __restrict__ bm,
    const int* __restrict__ degout,
    float* __restrict__ hdev, float* __restrict__ xn)
{
    __shared__ float sWm[80][64];
    __shared__ float spos[4][16];
    __shared__ float scf[4][64];
    const int tid = threadIdx.x;
    for (int i = tid; i < 5120; i += 256) sWm[i >> 6][i & 63] = Wm[i];
    const int n0 = blockIdx.x * 4;
    (&scf[0][0])[tid] = csif[(long)n0 * 64 + tid];
    if (tid < 64) {
        int dl = tid >> 4, o = tid & 15;
        int d = n0 + dl;
        float px = dpos[d * 2], py = dpos[d * 2 + 1], pk = (float)pkts[d];
        float v = bp[o] + px * Wp[o] + py * Wp[16 + o] + pk * Wp[32 + o];
        spos[dl][o] = fmaxf(v, 0.f);
    }
    __syncthreads();
    const int o = tid & 63, dl = tid >> 6;
    float h = bm[o];
    #pragma unroll
    for (int j = 0; j < 16; ++j) h += spos[dl][j] * sWm[j][o];
    #pragma unroll 8
    for (int j = 0; j < 64; ++j) h += scf[dl][j] * sWm[16 + j][o];
    h = fmaxf(h, 0.f);
    const long idx = (long)(n0 + dl) * 64 + o;
    hdev[idx] = h;
    xn[idx] = h * rsqrtf(fmaxf((float)degout[n0 + dl], 1.f));
}

__global__ void ap_enc_kernel(const float* __restrict__ appos,
                              const float* __restrict__ W, const float* __restrict__ b,
                              const int* __restrict__ degout,
                              float* __restrict__ hap, float* __restrict__ xnap)
{
    int tid = threadIdx.x;
    int a = tid >> 6, o = tid & 63;
    float v = fmaxf(b[o] + appos[a * 2] * W[o] + appos[a * 2 + 1] * W[64 + o], 0.f);
    hap[tid] = v;
    xnap[tid] = v * rsqrtf(fmaxf((float)degout[a], 1.f));
}

// ---------------------------------------------------------------------------
__global__ __launch_bounds__(256) void degrees_kernel(
    const int* __restrict__ dd_src, const int* __restrict__ dd_dst,
    const int* __restrict__ da_src, const int* __restrict__ da_dst,
    const int* __restrict__ ad_src, const int* __restrict__ ad_dst,
    int* deg_dd_out, int* deg_dd_in, int* deg_da_out, int* deg_ad_in, int* deg_small)
{
    __shared__ int s4[16];
    const int tid = threadIdx.x;
    if (tid < 16) s4[tid] = 0;
    __syncthreads();
    const int gid = blockIdx.x * 256 + tid;
    atomicAdd(&deg_dd_out[dd_src[gid]], 1);
    atomicAdd(&deg_dd_in[dd_dst[gid]], 1);
    if (gid < EDA) {
        atomicAdd(&deg_da_out[da_src[gid]], 1);
        atomicAdd(&s4[da_dst[gid]], 1);
        atomicAdd(&s4[8 + ad_src[gid]], 1);
        atomicAdd(&deg_ad_in[ad_dst[gid]], 1);
    }
    __syncthreads();
    if (tid < 16 && s4[tid] != 0) atomicAdd(&deg_small[tid], s4[tid]);
}

__global__ __launch_bounds__(1024) void scan_kernel(
    const int* __restrict__ degA, int* rsA, int* curA,
    const int* __restrict__ degB, int* rsB, int* curB)
{
    const int* deg = blockIdx.x ? degB : degA;
    int* rs = blockIdx.x ? rsB : rsA;
    int* cur = blockIdx.x ? curB : curA;
    __shared__ int sd[1024];
    const int tid = threadIdx.x;
    const int base = tid * 8;
    int v[8]; int s = 0;
    #pragma unroll
    for (int j = 0; j < 8; ++j) { v[j] = deg[base + j]; s += v[j]; }
    sd[tid] = s;
    __syncthreads();
    for (int off = 1; off < 1024; off <<= 1) {
        int t = (tid >= off) ? sd[tid - off] : 0;
        __syncthreads();
        sd[tid] += t;
        __syncthreads();
    }
    int ex = sd[tid] - s;
    #pragma unroll
    for (int j = 0; j < 8; ++j) { rs[base + j] = ex; cur[base + j] = ex; ex += v[j]; }
}

__global__ __launch_bounds__(256) void reorder_kernel(
    const int* __restrict__ src, const int* __restrict__ dst,
    int* __restrict__ cursor, int* __restrict__ ssrc, int nE)
{
    int e = blockIdx.x * 256 + threadIdx.x;
    if (e < nE) {
        int pos = atomicAdd(&cursor[dst[e]], 1);
        ssrc[pos] = src[e];
    }
}

// ---------------------------------------------------------------------------
__global__ __launch_bounds__(256) void gather_kernel(
    const int* __restrict__ row_start, const int* __restrict__ deg_in,
    const int* __restrict__ ssrc, const float* __restrict__ xn,
    float* __restrict__ agg)
{
    const int tid = threadIdx.x;
    const int w = __builtin_amdgcn_readfirstlane(tid >> 6);
    const int f = tid & 63;
    const int d = blockIdx.x * 4 + w;
    const int start = row_start[d], len = deg_in[d];
    float acc = 0.f;
    int j = 0;
    for (; j + 4 <= len; j += 4) {
        int s0 = ssrc[start + j], s1 = ssrc[start + j + 1];
        int s2 = ssrc[start + j + 2], s3 = ssrc[start + j + 3];
        float v0 = xn[(long)s0 * 64 + f], v1 = xn[(long)s1 * 64 + f];
        float v2 = xn[(long)s2 * 64 + f], v3 = xn[(long)s3 * 64 + f];
        acc += (v0 + v1) + (v2 + v3);
    }
    for (; j < len; ++j) acc += xn[(long)ssrc[start + j] * 64 + f];
    agg[(long)d * 64 + f] = acc * rsqrtf(fmaxf((float)len, 1.f));
}

__global__ __launch_bounds__(256) void da_reduce_kernel(
    const int* __restrict__ src, const int* __restrict__ dst,
    const float* __restrict__ x, const int* __restrict__ deg_out,
    float* __restrict__ agg)
{
    __shared__ float sacc[4][64];
    const int tid = threadIdx.x;
    (&sacc[0][0])[tid] = 0.f;
    __syncthreads();
    const int f = tid & 63;
    const int base = blockIdx.x * 128;
    for (int e = base + (tid >> 6); e < base + 128; e += 4) {
        int s = src[e], d = dst[e];
        float sc = rsqrtf(fmaxf((float)deg_out[s], 1.f));
        atomicAdd(&sacc[d][f], x[(long)s * 64 + f] * sc);
    }
    __syncthreads();
    float v = (&sacc[0][0])[tid];
    if (v != 0.f) atomicAdd(&agg[tid], v);
}

// ---------------------------------------------------------------------------
__global__ __launch_bounds__(256) void combine_hd_kernel(
    const float* __restrict__ agg1, const float* __restrict__ W1, const float* __restrict__ b1,
    const float* __restrict__ agg2, const float* __restrict__ W2, const float* __restrict__ b2,
    const int* __restrict__ degout, float* __restrict__ out, float* __restrict__ xnout)
{
    __shared__ float sW1[64][64];
    __shared__ float sW2[64][64];
    __shared__ float sa1[4][64];
    __shared__ float sa2[4][64];
    const int tid = threadIdx.x;
    for (int i = tid; i < 4096; i += 256) { sW1[i >> 6][i & 63] = W1[i]; sW2[i >> 6][i & 63] = W2[i]; }
    const int n0 = blockIdx.x * 4;
    (&sa1[0][0])[tid] = agg1[(long)n0 * 64 + tid];
    (&sa2[0][0])[tid] = agg2[(long)n0 * 64 + tid];
    __syncthreads();
    const int o = tid & 63, dl = tid >> 6;
    float acc1 = 0.f, acc2 = 0.f;
    #pragma unroll 8
    for (int k = 0; k < 64; ++k) {
        acc1 += sa1[dl][k] * sW1[k][o];
        acc2 += sa2[dl][k] * sW2[k][o];
    }
    float h = fmaxf(acc1 + acc2 + b1[o] + b2[o], 0.f);
    const long idx = (long)(n0 + dl) * 64 + o;
    out[idx] = h;
    if (xnout) xnout[idx] = h * rsqrtf(fmaxf((float)degout[n0 + dl], 1.f));
}

__global__ void combine_ha_kernel(const float* __restrict__ agg, const int* __restrict__ degin,
                                  const float* __restrict__ W, const float* __restrict__ b,
                                  const int* __restrict__ degout,
                                  float* __restrict__ out, float* __restrict__ xnout)
{
    const int tid = threadIdx.x;
    const int o = tid & 63, a = tid >> 6;
    float acc = 0.f;
    for (int k = 0; k < 64; ++k) acc += agg[a * 64 + k] * W[k * 64 + o];
    float r = rsqrtf(fmaxf((float)degin[a], 1.f));
    float h = fmaxf(acc * r + b[o], 0.f);
    out[tid] = h;
    xnout[tid] = h * rsqrtf(fmaxf((float)degout[a], 1.f));
}

// ---------------------------------------------------------------------------
__global__ __launch_bounds__(256) void head_kernel(
    const float* __restrict__ hd2,
    const float* __restrict__ W1, const float* __restrict__ b1,
    const float* __restrict__ W2, const float* __restrict__ b2,
    float* __restrict__ logits_out)
{
    __shared__ float sW1[64][64];
    __shared__ float sW2[64][32];
    __shared__ float sh[4][64];
    __shared__ float st[4][64];
    const int tid = threadIdx.x;
    for (int i = tid; i < 4096; i += 256) sW1[i >> 6][i & 63] = W1[i];
    for (int i = tid; i < 2048; i += 256) sW2[i >> 5][i & 31] = W2[i];
    const int n0 = blockIdx.x * 4;
    (&sh[0][0])[tid] = hd2[(long)n0 * 64 + tid];
    __syncthreads();
    const int o = tid & 63, dl = tid >> 6;
    float acc = b1[o];
    #pragma unroll 8
    for (int k = 0; k < 64; ++k) acc += sh[dl][k] * sW1[k][o];
    st[dl][o] = fmaxf(acc, 0.f);
    __syncthreads();
    if (tid < 128) {
        int j = tid & 31, d2 = tid >> 5;
        float a2 = b2[j];
        #pragma unroll 8
        for (int k = 0; k < 64; ++k) a2 += st[d2][k] * sW2[k][j];
        logits_out[(long)(n0 + d2) * 32 + j] = a2;
    }
}

// ---------------------------------------------------------------------------
__global__ __launch_bounds__(1024) void softmax_stats_kernel(
    const float* __restrict__ logits,
    float* __restrict__ smax, int* __restrict__ sargm, float* __restrict__ ssum)
{
    __shared__ float smx[1024];
    __shared__ int sid[1024];
    __shared__ float ssm[1024];
    const int j = blockIdx.x;
    const int tid = threadIdx.x;
    float best = -__builtin_inff(); int bid = 0x7fffffff;
    for (int n = tid; n < NDEV; n += 1024) {
        float v = logits[n * 32 + j];
        if (v > best) { best = v; bid = n; }
    }
    smx[tid] = best; sid[tid] = bid;
    __syncthreads();
    for (int s = 512; s > 0; s >>= 1) {
        if (tid < s) {
            float v2 = smx[tid + s]; int i2 = sid[tid + s];
            if (v2 > smx[tid] || (v2 == smx[tid] && i2 < sid[tid])) { smx[tid] = v2; sid[tid] = i2; }
        }
        __syncthreads();
    }
    const float mx = smx[0];
    float part = 0.f;
    for (int n = tid; n < NDEV; n += 1024) part += expf(logits[n * 32 + j] - mx);
    ssm[tid] = part;
    __syncthreads();
    for (int s = 512; s > 0; s >>= 1) {
        if (tid < s) ssm[tid] += ssm[tid + s];
        __syncthreads();
    }
    if (tid == 0) { smax[j] = mx; sargm[j] = sid[0]; ssum[j] = ssm[0]; }
}

__global__ __launch_bounds__(256) void final_kernel(
    const float* __restrict__ logits, const float* __restrict__ smax,
    const int* __restrict__ sargm, const float* __restrict__ ssum,
    float* __restrict__ hard, float* __restrict__ soft)
{
    const int gid = blockIdx.x * 256 + threadIdx.x;
    const int n = gid >> 3, t = gid & 7;
    float s = 0.f; int h = 0;
    #pragma unroll
    for (int a = 0; a < 4; ++a) {
        int j = t * 4 + a;
        s += expf(logits[n * 32 + j] - smax[j]) / ssum[j];
        h |= (sargm[j] == n) ? 1 : 0;
    }
    hard[gid] = (float)h;
    soft[gid] = s;
}

// ---------------------------------------------------------------------------
extern "C" void kernel_launch(void* const* d_in, const int* in_sizes, int n_in,
                              void* d_out, int out_size, void* d_ws, size_t ws_size,
                              hipStream_t stream)
{
    const float* device_pos = (const float*)d_in[0];
    const float* ap_pos     = (const float*)d_in[1];
    const float* csi        = (const float*)d_in[2];
    const int*   node_pk    = (const int*)d_in[3];
    const int* dd_src = (const int*)d_in[4];
    const int* dd_dst = (const int*)d_in[5];
    const int* da_src = (const int*)d_in[6];
    const int* da_dst = (const int*)d_in[7];
    const int* ad_src = (const int*)d_in[8];
    const int* ad_dst = (const int*)d_in[9];
    const float* w1  = (const float*)d_in[10]; const float* b1  = (const float*)d_in[11];
    const float* w2  = (const float*)d_in[12]; const float* b2  = (const float*)d_in[13];
    const float* fcW = (const float*)d_in[14]; const float* fcb = (const float*)d_in[15];
    const float* Wp  = (const float*)d_in[16]; const float* bp  = (const float*)d_in[17];
    const float* Wc  = (const float*)d_in[18]; const float* bc  = (const float*)d_in[19];
    const float* Wm  = (const float*)d_in[20]; const float* bm  = (const float*)d_in[21];
    const float* Wap = (const float*)d_in[22]; const float* bap = (const float*)d_in[23];
    const float* g1ddW = (const float*)d_in[24]; const float* g1ddb = (const float*)d_in[25];
    const float* g1daW = (const float*)d_in[26]; const float* g1dab = (const float*)d_in[27];
    const float* g1adW = (const float*)d_in[28]; const float* g1adb = (const float*)d_in[29];
    const float* g2ddW = (const float*)d_in[30]; const float* g2ddb = (const float*)d_in[31];
    const float* g2adW = (const float*)d_in[34]; const float* g2adb = (const float*)d_in[35];
    const float* a1W = (const float*)d_in[36]; const float* a1b = (const float*)d_in[37];
    const float* a2W = (const float*)d_in[38]; const float* a2b = (const float*)d_in[39];

    float* ws = (float*)d_ws;
    size_t o_c2    = 0;                               // 16,777,216
    size_t o_emb   = o_c2 + (size_t)CHUNK * 2048;
    size_t o_csif  = o_emb + (size_t)NSAMP * 64;
    size_t o_hdev  = o_csif + (size_t)NDEV * 64;
    size_t o_hap   = o_hdev + (size_t)NDEV * 64;      // 256
    size_t o_hd1   = o_hap + 256;
    size_t o_ha1   = o_hd1 + (size_t)NDEV * 64;       // 256
    size_t o_hd2   = o_ha1 + 256;
    size_t o_aggdd = o_hd2 + (size_t)NDEV * 64;
    size_t o_aggad = o_aggdd + (size_t)NDEV * 64;
    size_t o_xn    = o_aggad + (size_t)NDEV * 64;
    size_t o_xnap  = o_xn + (size_t)NDEV * 64;        // 256
    size_t o_wpk   = o_xnap + 256;                    // 4608
    // zero region
    size_t o_zero  = o_wpk + 4608;
    size_t o_degddo = o_zero;
    size_t o_degddi = o_degddo + NDEV;
    size_t o_degdao = o_degddi + NDEV;
    size_t o_degadi = o_degdao + NDEV;
    size_t o_degsm  = o_degadi + NDEV;        // int[16]
    size_t o_aggda  = o_degsm + 16;           // float[256]
    size_t o_zend   = o_aggda + 256;
    // non-zeroed
    size_t o_rsdd  = o_zend;
    size_t o_curdd = o_rsdd + NDEV;
    size_t o_rsad  = o_curdd + NDEV;
    size_t o_curad = o_rsad + NDEV;
    size_t o_ssdd  = o_curad + NDEV;          // int[262144]
    size_t o_ssad  = o_ssdd + EDD;            // int[32768]
    size_t o_smax  = o_ssad + EAD;
    size_t o_ssum  = o_smax + 32;
    size_t o_sargm = o_ssum + 32;

    float* out = (float*)d_out;
    float* out_hard   = out;                 // [8192][8]
    float* out_logits = out + 65536;         // [8192][32]
    float* out_soft   = out + 65536 + 262144;

    hipMemsetAsync((void*)(ws + o_zero), 0, (o_zend - o_zero) * sizeof(float), stream);
    repack_kernel<<<18, 256, 0, stream>>>(w2, ws + o_wpk);

    // graph prep
    degrees_kernel<<<EDD / 256, 256, 0, stream>>>(dd_src, dd_dst, da_src, da_dst, ad_src, ad_dst,
                                                  (int*)(ws + o_degddo), (int*)(ws + o_degddi),
                                                  (int*)(ws + o_degdao), (int*)(ws + o_degadi),
                                                  (int*)(ws + o_degsm));
    scan_kernel<<<2, 1024, 0, stream>>>((int*)(ws + o_degddi), (int*)(ws + o_rsdd), (int*)(ws + o_curdd),
                                        (int*)(ws + o_degadi), (int*)(ws + o_rsad), (int*)(ws + o_curad));
    reorder_kernel<<<EDD / 256, 256, 0, stream>>>(dd_src, dd_dst, (int*)(ws + o_curdd),
                                                  (int*)(ws + o_ssdd), EDD);
    reorder_kernel<<<EAD / 256, 256, 0, stream>>>(ad_src, ad_dst, (int*)(ws + o_curad),
                                                  (int*)(ws + o_ssad), EAD);

    // CSI encoder
    for (int c = 0; c < NSAMP / CHUNK; ++c) {
        const float* csi_c = csi + (size_t)c * CHUNK * 128;
        float* emb_c = ws + o_emb + (size_t)c * CHUNK * 64;
        conv_kernel<<<CHUNK / 4, 256, 0, stream>>>(csi_c, ws + o_c2, w1, b1, ws + o_wpk, b2);
        fc16_kernel<<<CHUNK / 16, 256, 0, stream>>>(ws + o_c2, fcW, fcb, emb_c, 2048);
    }

    // device encoder
    fc16_kernel<<<NDEV / 16, 256, 0, stream>>>(ws + o_emb, Wc, bc, ws + o_csif, 256);
    merge_kernel<<<NDEV / 4, 256, 0, stream>>>(device_pos, node_pk, ws + o_csif,
                                               Wp, bp, Wm, bm, (int*)(ws + o_degddo),
                                               ws + o_hdev, ws + o_xn);
    ap_enc_kernel<<<1, 256, 0, stream>>>(ap_pos, Wap, bap, (int*)(ws + o_degsm) + 8,
                                         ws + o_hap, ws + o_xnap);

    // layer 1
    gather_kernel<<<NDEV / 4, 256, 0, stream>>>((int*)(ws + o_rsdd), (int*)(ws + o_degddi),
                                                (int*)(ws + o_ssdd), ws + o_xn, ws + o_aggdd);
    gather_kernel<<<NDEV / 4, 256, 0, stream>>>((int*)(ws + o_rsad), (int*)(ws + o_degadi),
                                                (int*)(ws + o_ssad), ws + o_xnap, ws + o_aggad);
    da_reduce_kernel<<<EDA / 128, 256, 0, stream>>>(da_src, da_dst, ws + o_hdev,
                                                    (int*)(ws + o_degdao), ws + o_aggda);
    combine_hd_kernel<<<NDEV / 4, 256, 0, stream>>>(ws + o_aggdd, g1ddW, g1ddb,
                                                    ws + o_aggad, g1adW, g1adb,
                                                    (int*)(ws + o_degddo), ws + o_hd1, ws + o_xn);
    combine_ha_kernel<<<1, 256, 0, stream>>>(ws + o_aggda, (int*)(ws + o_degsm),
                                             g1daW, g1dab, (int*)(ws + o_degsm) + 8,
                                             ws + o_ha1, ws + o_xnap);

    // layer 2
    gather_kernel<<<NDEV / 4, 256, 0, stream>>>((int*)(ws + o_rsdd), (int*)(ws + o_degddi),
                                                (int*)(ws + o_ssdd), ws + o_xn, ws + o_aggdd);
    gather_kernel<<<NDEV / 4, 256, 0, stream>>>((int*)(ws + o_rsad), (int*)(ws + o_degadi),
                                                (int*)(ws + o_ssad), ws + o_xnap, ws + o_aggad);
    combine_hd_kernel<<<NDEV / 4, 256, 0, stream>>>(ws + o_aggdd, g2ddW, g2ddb,
                                                    ws + o_aggad, g2adW, g2adb,
                                                    (int*)(ws + o_degddo), ws + o_hd2, nullptr);

    head_kernel<<<NDEV / 4, 256, 0, stream>>>(ws + o_hd2, a1W, a1b, a2W, a2b, out_logits);

    softmax_stats_kernel<<<32, 1024, 0, stream>>>(out_logits, ws + o_smax,
                                                  (int*)(ws + o_sargm), ws + o_ssum);
    final_kernel<<<65536 / 256, 256, 0, stream>>>(out_logits, ws + o_smax,
                                                  (int*)(ws + o_sargm), ws + o_ssum,
                                                  out_hard, out_soft);
    (void)in_sizes; (void)n_in; (void)out_size; (void)ws_size;
}